// Round 1
// baseline (176.297 us; speedup 1.0000x reference)
//
#include <hip/hip_runtime.h>

// BPR sequence loss:
//   pos = dot(seq[b,l], table[target[b,l]])
//   neg_k = dot(seq[b,l], table[neg[b,l,k]])
//   loss = mean over masked (b,l,k) of -log(sigmoid(pos - neg_k) + 1e-8)
//
// B=32, L=200, K=100, D=64, V=1e6. Dominant cost: 640k random 256B row
// gathers from the 256MB table -> memory/gather bound.

constexpr int B = 32;
constexpr int L = 200;
constexpr int K = 100;
constexpr int D = 64;
#define EPS 1e-8f

__global__ __launch_bounds__(256) void bpr_loss_kernel(
    const float* __restrict__ seq,     // [B*L, D]
    const float* __restrict__ table,   // [V, D]
    const float* __restrict__ mask,    // [B*L]
    const int*   __restrict__ target,  // [B*L]
    const int*   __restrict__ neg,     // [B*L, K]
    double*      __restrict__ acc)     // acc[0]=masked loss sum, acc[1]=mask count sum
{
    const int bl     = blockIdx.x;        // one (b,l) per block
    const int tid    = threadIdx.x;       // 256 threads = 16 groups x 16 lanes
    const int lane16 = tid & 15;
    const int group  = tid >> 4;

    __shared__ float s_pos;
    __shared__ float s_part[16];

    // Per-lane fragment of the sequence vector (row is 256B, 16 lanes x float4).
    const float4 sv = *reinterpret_cast<const float4*>(seq + (size_t)bl * D + lane16 * 4);

    // Positive score: group 0 gathers the target row and dots it.
    if (group == 0) {
        const int pidx = target[bl];
        const float4 pv = *reinterpret_cast<const float4*>(table + (size_t)pidx * D + lane16 * 4);
        float d = sv.x * pv.x + sv.y * pv.y + sv.z * pv.z + sv.w * pv.w;
        #pragma unroll
        for (int off = 1; off < 16; off <<= 1)
            d += __shfl_xor(d, off, 64);
        if (lane16 == 0) s_pos = d;
    }
    __syncthreads();
    const float pos = s_pos;

    // Negative scores: group g handles k = g, g+16, ...
    float lsum = 0.0f;
    for (int k = group; k < K; k += 16) {
        const int nidx = neg[(size_t)bl * K + k];
        const float4 nv = *reinterpret_cast<const float4*>(table + (size_t)nidx * D + lane16 * 4);
        float d = sv.x * nv.x + sv.y * nv.y + sv.z * nv.z + sv.w * nv.w;
        #pragma unroll
        for (int off = 1; off < 16; off <<= 1)
            d += __shfl_xor(d, off, 64);
        if (lane16 == 0) {
            const float diff = pos - d;
            const float sig  = 1.0f / (1.0f + expf(-diff));
            lsum += -logf(sig + EPS);
        }
    }

    if (lane16 == 0) s_part[group] = lsum;
    __syncthreads();

    if (tid == 0) {
        float bsum = 0.0f;
        #pragma unroll
        for (int i = 0; i < 16; ++i) bsum += s_part[i];
        const float m = mask[bl];
        atomicAdd(&acc[0], (double)(bsum * m));
        atomicAdd(&acc[1], (double)(m * (float)K));
    }
}

__global__ void finalize_kernel(const double* __restrict__ acc, float* __restrict__ out) {
    if (threadIdx.x == 0 && blockIdx.x == 0) {
        const double denom = acc[1];
        out[0] = (float)(denom != 0.0 ? acc[0] / denom : 0.0);
    }
}

extern "C" void kernel_launch(void* const* d_in, const int* in_sizes, int n_in,
                              void* d_out, int out_size, void* d_ws, size_t ws_size,
                              hipStream_t stream) {
    const float* seq    = (const float*)d_in[0];
    const float* table  = (const float*)d_in[1];
    const float* mask   = (const float*)d_in[2];
    const int*   target = (const int*)d_in[3];
    const int*   neg    = (const int*)d_in[4];
    double* acc = (double*)d_ws;

    hipMemsetAsync(acc, 0, 2 * sizeof(double), stream);
    bpr_loss_kernel<<<B * L, 256, 0, stream>>>(seq, table, mask, target, neg, acc);
    finalize_kernel<<<1, 64, 0, stream>>>(acc, (float*)d_out);
}

// Round 2
// 46.281 us; speedup vs baseline: 3.8093x; 3.8093x over previous
//
#include <hip/hip_runtime.h>

// BPR sequence loss:
//   pos = dot(seq[b,l], table[target[b,l]])
//   neg_k = dot(seq[b,l], table[neg[b,l,k]])
//   loss = mean over masked (b,l,k) of -log(sigmoid(pos - neg_k) + 1e-8)
//
// B=32, L=200, K=100, D=64, V=1e6.
// R1 finding: table gathers are L3-resident after warm-up (hbm ~0); 176us was
// NOT memory BW. Suspect: 12800 serialized same-address f64 atomics (~30cyc
// each at LLC ~= 384k cyc ~= measured 423k cyc). This round: per-block partial
// writes + separate reduce kernel, no global atomics. Everything else identical.

constexpr int B = 32;
constexpr int L = 200;
constexpr int K = 100;
constexpr int D = 64;
constexpr int BL = B * L;
#define EPS 1e-8f

__global__ __launch_bounds__(256) void bpr_loss_kernel(
    const float* __restrict__ seq,     // [B*L, D]
    const float* __restrict__ table,   // [V, D]
    const float* __restrict__ mask,    // [B*L]
    const int*   __restrict__ target,  // [B*L]
    const int*   __restrict__ neg,     // [B*L, K]
    float*       __restrict__ partial) // [B*L] masked per-(b,l) loss sums
{
    const int bl     = blockIdx.x;        // one (b,l) per block
    const int tid    = threadIdx.x;       // 256 threads = 16 groups x 16 lanes
    const int lane16 = tid & 15;
    const int group  = tid >> 4;

    __shared__ float s_pos;
    __shared__ float s_part[16];

    // Per-lane fragment of the sequence vector (row is 256B, 16 lanes x float4).
    const float4 sv = *reinterpret_cast<const float4*>(seq + (size_t)bl * D + lane16 * 4);

    // Positive score: group 0 gathers the target row and dots it.
    if (group == 0) {
        const int pidx = target[bl];
        const float4 pv = *reinterpret_cast<const float4*>(table + (size_t)pidx * D + lane16 * 4);
        float d = sv.x * pv.x + sv.y * pv.y + sv.z * pv.z + sv.w * pv.w;
        #pragma unroll
        for (int off = 1; off < 16; off <<= 1)
            d += __shfl_xor(d, off, 64);
        if (lane16 == 0) s_pos = d;
    }
    __syncthreads();
    const float pos = s_pos;

    // Negative scores: group g handles k = g, g+16, ...
    float lsum = 0.0f;
    for (int k = group; k < K; k += 16) {
        const int nidx = neg[(size_t)bl * K + k];
        const float4 nv = *reinterpret_cast<const float4*>(table + (size_t)nidx * D + lane16 * 4);
        float d = sv.x * nv.x + sv.y * nv.y + sv.z * nv.z + sv.w * nv.w;
        #pragma unroll
        for (int off = 1; off < 16; off <<= 1)
            d += __shfl_xor(d, off, 64);
        if (lane16 == 0) {
            const float diff = pos - d;
            const float sig  = 1.0f / (1.0f + expf(-diff));
            lsum += -logf(sig + EPS);
        }
    }

    if (lane16 == 0) s_part[group] = lsum;
    __syncthreads();

    if (tid == 0) {
        float bsum = 0.0f;
        #pragma unroll
        for (int i = 0; i < 16; ++i) bsum += s_part[i];
        partial[bl] = bsum * mask[bl];   // plain store, no atomics
    }
}

// Single-block reduction of the 6400 partials + mask sum -> final scalar.
__global__ __launch_bounds__(256) void reduce_kernel(
    const float* __restrict__ partial,  // [BL]
    const float* __restrict__ mask,     // [BL]
    float*       __restrict__ out)
{
    const int tid = threadIdx.x;
    float lsum = 0.0f, msum = 0.0f;
    for (int i = tid; i < BL; i += 256) {
        lsum += partial[i];
        msum += mask[i];
    }
    // wave-level reduce (64 lanes)
    #pragma unroll
    for (int off = 1; off < 64; off <<= 1) {
        lsum += __shfl_xor(lsum, off, 64);
        msum += __shfl_xor(msum, off, 64);
    }
    __shared__ float s_l[4], s_m[4];
    const int wave = tid >> 6;
    if ((tid & 63) == 0) { s_l[wave] = lsum; s_m[wave] = msum; }
    __syncthreads();
    if (tid == 0) {
        float tl = s_l[0] + s_l[1] + s_l[2] + s_l[3];
        float tm = s_m[0] + s_m[1] + s_m[2] + s_m[3];
        const float denom = tm * (float)K;
        out[0] = (denom != 0.0f) ? tl / denom : 0.0f;
    }
}

extern "C" void kernel_launch(void* const* d_in, const int* in_sizes, int n_in,
                              void* d_out, int out_size, void* d_ws, size_t ws_size,
                              hipStream_t stream) {
    const float* seq    = (const float*)d_in[0];
    const float* table  = (const float*)d_in[1];
    const float* mask   = (const float*)d_in[2];
    const int*   target = (const int*)d_in[3];
    const int*   neg    = (const int*)d_in[4];
    float* partial = (float*)d_ws;   // BL floats

    bpr_loss_kernel<<<BL, 256, 0, stream>>>(seq, table, mask, target, neg, partial);
    reduce_kernel<<<1, 256, 0, stream>>>(partial, mask, (float*)d_out);
}

// Round 3
// 33.228 us; speedup vs baseline: 5.3056x; 1.3928x over previous
//
#include <hip/hip_runtime.h>

// BPR sequence loss. B=32, L=200, K=100, D=64, V=1e6.
// R1: same-address f64 atomics were the 176us bottleneck -> per-block partials (46us).
// R3: raise gather MLP (all 8 row loads in flight, no pos/neg barrier), DPP
//     rotate-reduce instead of ds_swizzle shuffles, single transcendental pass
//     per group (lane j computes loss for neg j after allsum broadcast).

constexpr int B = 32;
constexpr int L = 200;
constexpr int K = 100;
constexpr int D = 64;
constexpr int BL = B * L;

// DPP row_ror:n add — rotate within 16-lane row, single VALU instruction.
template<int CTRL>
__device__ __forceinline__ float dpp_add(float v) {
    int r = __builtin_amdgcn_update_dpp(0, __builtin_bit_cast(int, v), CTRL, 0xF, 0xF, true);
    return v + __builtin_bit_cast(float, r);
}
// After this, EVERY lane of the 16-lane group holds the group sum.
__device__ __forceinline__ float group16_allsum(float v) {
    v = dpp_add<0x121>(v);  // row_ror:1
    v = dpp_add<0x122>(v);  // row_ror:2
    v = dpp_add<0x124>(v);  // row_ror:4
    v = dpp_add<0x128>(v);  // row_ror:8
    return v;
}

__device__ __forceinline__ float dot4(float4 a, float4 b) {
    return a.x * b.x + a.y * b.y + a.z * b.z + a.w * b.w;
}

__global__ __launch_bounds__(256) void bpr_loss_kernel(
    const float* __restrict__ seq,     // [B*L, D]
    const float* __restrict__ table,   // [V, D]
    const float* __restrict__ mask,    // [B*L]
    const int*   __restrict__ target,  // [B*L]
    const int*   __restrict__ neg,     // [B*L, K]
    float*       __restrict__ partial) // [B*L]
{
    const int bl     = blockIdx.x;
    const int tid    = threadIdx.x;    // 256 threads = 16 groups x 16 lanes
    const int lane16 = tid & 15;
    const int group  = tid >> 4;

    const float4 sv = *reinterpret_cast<const float4*>(seq + (size_t)bl * D + lane16 * 4);

    // Indices: pos + up to 7 negs for this group (k = group + 16*j).
    const int  base = bl * K + group;
    const int  pidx = target[bl];
    const bool has7 = (group < 4);     // k = group+96 < 100 only for groups 0..3
    int nidx[7];
    #pragma unroll
    for (int j = 0; j < 6; ++j) nidx[j] = neg[base + 16 * j];
    nidx[6] = has7 ? neg[base + 96] : 0;

    // Issue all 8 gathers back-to-back (32 VGPRs of payload in flight).
    const int doff = lane16 * 4;
    float4 pv = *reinterpret_cast<const float4*>(table + (size_t)pidx * D + doff);
    float4 nv[7];
    #pragma unroll
    for (int j = 0; j < 7; ++j)
        nv[j] = *reinterpret_cast<const float4*>(table + (size_t)nidx[j] * D + doff);

    // Dot fragments + group-wide allsum (broadcasts result to all 16 lanes).
    float dp = group16_allsum(dot4(sv, pv));
    float dn[7];
    #pragma unroll
    for (int j = 0; j < 7; ++j) dn[j] = group16_allsum(dot4(sv, nv[j]));

    // Lane j (j<7) computes the loss for neg j — one transcendental pass per group.
    const int j = lane16;
    float b0 = (j & 1) ? dn[1] : dn[0];
    float b1 = (j & 1) ? dn[3] : dn[2];
    float b2 = (j & 1) ? dn[5] : dn[4];
    float b3 = dn[6];
    float c0 = (j & 2) ? b1 : b0;
    float c1 = (j & 2) ? b3 : b2;
    float dneg = (j & 4) ? c1 : c0;

    const bool valid = (j < 6) | ((j == 6) & has7);
    // -log(sigmoid(x)+eps) = log(1+t) - log(1+eps*(1+t)),  t = e^{-x}
    // clamp exponent so t stays finite (result saturates at -log(eps)=18.42, as ref does)
    const float x = dp - dneg;
    const float t = __expf(fminf(-x, 80.0f));
    const float u = 1.0f + t;
    float lss = __logf(u) - __logf(fmaf(1e-8f, u, 1.0f));
    lss = valid ? lss : 0.0f;

    // group sum -> wave sum -> block sum
    lss = group16_allsum(lss);
    lss += __shfl_xor(lss, 16, 64);
    lss += __shfl_xor(lss, 32, 64);

    __shared__ float s_wave[4];
    if ((tid & 63) == 0) s_wave[tid >> 6] = lss;
    __syncthreads();
    if (tid == 0)
        partial[bl] = (s_wave[0] + s_wave[1] + s_wave[2] + s_wave[3]) * mask[bl];
}

__global__ __launch_bounds__(256) void reduce_kernel(
    const float* __restrict__ partial,  // [BL]
    const float* __restrict__ mask,     // [BL]
    float*       __restrict__ out)
{
    const int tid = threadIdx.x;
    const float4* p4 = reinterpret_cast<const float4*>(partial);
    const float4* m4 = reinterpret_cast<const float4*>(mask);
    float lsum = 0.0f, msum = 0.0f;
    for (int i = tid; i < BL / 4; i += 256) {
        float4 a = p4[i];
        float4 b = m4[i];
        lsum += (a.x + a.y) + (a.z + a.w);
        msum += (b.x + b.y) + (b.z + b.w);
    }
    #pragma unroll
    for (int off = 1; off < 64; off <<= 1) {
        lsum += __shfl_xor(lsum, off, 64);
        msum += __shfl_xor(msum, off, 64);
    }
    __shared__ float s_l[4], s_m[4];
    const int wave = tid >> 6;
    if ((tid & 63) == 0) { s_l[wave] = lsum; s_m[wave] = msum; }
    __syncthreads();
    if (tid == 0) {
        float tl = s_l[0] + s_l[1] + s_l[2] + s_l[3];
        float tm = s_m[0] + s_m[1] + s_m[2] + s_m[3];
        const float denom = tm * (float)K;
        out[0] = (denom != 0.0f) ? tl / denom : 0.0f;
    }
}

extern "C" void kernel_launch(void* const* d_in, const int* in_sizes, int n_in,
                              void* d_out, int out_size, void* d_ws, size_t ws_size,
                              hipStream_t stream) {
    const float* seq    = (const float*)d_in[0];
    const float* table  = (const float*)d_in[1];
    const float* mask   = (const float*)d_in[2];
    const int*   target = (const int*)d_in[3];
    const int*   neg    = (const int*)d_in[4];
    float* partial = (float*)d_ws;   // BL floats

    bpr_loss_kernel<<<BL, 256, 0, stream>>>(seq, table, mask, target, neg, partial);
    reduce_kernel<<<1, 256, 0, stream>>>(partial, mask, (float*)d_out);
}